// Round 11
// baseline (256.027 us; speedup 1.0000x reference)
//
#include <hip/hip_runtime.h>

// ============================================================================
// EfficientAttention: x->(QKV proj)->LN(q)->flash attention->(+q)->out proj
// B=2, N=2048, D=1024, H=16, d=64.  bf16 MFMA pipeline, fp32 accumulate.
// R11: attention back to R9's LDS-free/barrier-free one-wave blocks, but with
//      32 q-rows per wave (2 subtiles) and grid 2048 (q split across BLOCKS,
//      the axis needing no merge): 8 blocks/CU of work vs R9's 4, lower VGPR,
//      zero LDS/barriers. R10's wave-split + LDS merge is reverted (it lost
//      residency: ~1 block/CU from 50KB LDS + 156 VGPR, epilogue serialized).
// ============================================================================

typedef unsigned short u16;
typedef __attribute__((ext_vector_type(8))) short bf8v;   // 8 bf16 (bit-pattern shorts)
typedef __attribute__((ext_vector_type(4))) float f4v;    // MFMA acc

typedef __attribute__((address_space(1))) void gvoid;
typedef __attribute__((address_space(3))) void lvoid;
__device__ __forceinline__ void cp16(const void* g, void* l) {
  __builtin_amdgcn_global_load_lds((gvoid*)g, (lvoid*)l, 16, 0, 0);
}

__device__ __forceinline__ float bf2f(u16 u) {
  unsigned int x = ((unsigned int)u) << 16;
  float f; __builtin_memcpy(&f, &x, 4); return f;
}
__device__ __forceinline__ u16 f2bf(float f) {
  unsigned int x; __builtin_memcpy(&x, &f, 4);
  unsigned int r = (x + 0x7fffu + ((x >> 16) & 1u)) >> 16;   // RNE
  return (u16)r;
}
// pack 2 floats' bf16 truncations into one u32 (a -> low16, b -> high16)
__device__ __forceinline__ unsigned pack2bf(float a, float b) {
  unsigned ua, ub;
  __builtin_memcpy(&ua, &a, 4); __builtin_memcpy(&ub, &b, 4);
  return __builtin_amdgcn_perm(ub, ua, 0x07060302u);
}

#define KSCALE 0.18033688011f   // log2(e) / sqrt(64)

// ---------------------------------------------------------------------------
// dtype classifier: flags[t]=1 if tensor t looks like bf16, 0 if fp32.
// ---------------------------------------------------------------------------
__global__ void k_classify(const u16* a0, const u16* a1, const u16* a2, const u16* a3,
                           const u16* a4, const u16* a5, const u16* a6, const u16* a7,
                           const u16* a8, const u16* a9, const u16* a10, int* flags) {
  int t = threadIdx.x;
  if (t >= 11) return;
  const u16* arr[11] = {a0,a1,a2,a3,a4,a5,a6,a7,a8,a9,a10};
  const u16* p = arr[t];
  int ze = 0, no = 0, pe = 0;
  for (int i = 0; i < 128; ++i) {
    u16 he = p[2*i], ho = p[2*i+1];
    if (he == 0) ze++;
    if (ho != 0) no++;
    int e = (he >> 7) & 0xff;
    if (he == 0 || (e >= 64 && e <= 160)) pe++;
  }
  int isbf;
  if (ze >= 100 && no >= 64) isbf = 0;          // fp32 clean constants
  else isbf = (pe >= 100) ? 1 : 0;
  flags[t] = isbf;
}

// x (4M elems) -> bf16 ws copy, 8 elems/thread
__global__ __launch_bounds__(256) void k_convert_x(const void* xin, u16* xb, const int* flags) {
  size_t i = ((size_t)blockIdx.x * 256 + threadIdx.x) * 8;
  if (flags[0]) {
    *(float4*)(xb + i) = *((const float4*)((const u16*)xin + i));
  } else {
    const float* xf = (const float*)xin;
    float4 a = *(const float4*)(xf + i);
    float4 b = *(const float4*)(xf + i + 4);
    ushort4 o0, o1;
    o0.x = f2bf(a.x); o0.y = f2bf(a.y); o0.z = f2bf(a.z); o0.w = f2bf(a.w);
    o1.x = f2bf(b.x); o1.y = f2bf(b.y); o1.z = f2bf(b.z); o1.w = f2bf(b.w);
    *(ushort4*)(xb + i) = o0; *(ushort4*)(xb + i + 4) = o1;
  }
}

// W[k][n] (1024x1024) -> Wt[n][k] bf16, LDS 64x64 tile (pad 65 => 2-way banks)
__global__ __launch_bounds__(256) void k_transpose_w(const void* W0, const void* W1,
    const void* W2, const void* W3, u16* wt, const int* flags) {
  __shared__ u16 tile[64 * 65];
  int z = blockIdx.z;
  const void* W = (z == 0) ? W0 : (z == 1) ? W1 : (z == 2) ? W2 : W3;
  int isb = flags[1 + 2*z];
  u16* dst = wt + (size_t)z * (1u << 20);
  int r0 = blockIdx.y * 64, c0 = blockIdx.x * 64;
  int t = threadIdx.x;
  for (int rr = 0; rr < 2; ++rr) {
    int row = rr * 32 + (t >> 3);
    int c8 = (t & 7) * 8;
    u16 v[8];
    if (isb) {
      const u16* Ws = (const u16*)W;
      ushort4 a = *(const ushort4*)&Ws[(size_t)(r0 + row) * 1024 + c0 + c8];
      ushort4 b = *(const ushort4*)&Ws[(size_t)(r0 + row) * 1024 + c0 + c8 + 4];
      v[0]=a.x; v[1]=a.y; v[2]=a.z; v[3]=a.w; v[4]=b.x; v[5]=b.y; v[6]=b.z; v[7]=b.w;
    } else {
      const float* Wf = (const float*)W;
      float4 a = *(const float4*)&Wf[(size_t)(r0 + row) * 1024 + c0 + c8];
      float4 b = *(const float4*)&Wf[(size_t)(r0 + row) * 1024 + c0 + c8 + 4];
      v[0]=f2bf(a.x); v[1]=f2bf(a.y); v[2]=f2bf(a.z); v[3]=f2bf(a.w);
      v[4]=f2bf(b.x); v[5]=f2bf(b.y); v[6]=f2bf(b.z); v[7]=f2bf(b.w);
    }
#pragma unroll
    for (int j = 0; j < 8; ++j) tile[row * 65 + c8 + j] = v[j];
  }
  __syncthreads();
  for (int rr = 0; rr < 2; ++rr) {
    int nrow = rr * 32 + (t >> 3);
    int k8 = (t & 7) * 8;
    u16 v[8];
#pragma unroll
    for (int j = 0; j < 8; ++j) v[j] = tile[(k8 + j) * 65 + nrow];
    ushort4 o0, o1;
    o0.x=v[0]; o0.y=v[1]; o0.z=v[2]; o0.w=v[3];
    o1.x=v[4]; o1.y=v[5]; o1.z=v[6]; o1.w=v[7];
    *(ushort4*)&dst[(size_t)(c0 + nrow) * 1024 + r0 + k8] = o0;
    *(ushort4*)&dst[(size_t)(c0 + nrow) * 1024 + r0 + k8 + 4] = o1;
  }
}

// ---------------------------------------------------------------------------
// MTx128-tile gemm_bt: C[M,1024] = A[M,1024] @ Bt[1024,1024]^T + bias
// BK=32, double-buffered LDS, ONE barrier per K-iter.
// mode: 0 = fp32 rowmajor, 1 = bf16 rowmajor, 2 = bf16 scatter to vF
// ---------------------------------------------------------------------------
template <int MT>
__device__ __forceinline__ void gemm_bt(const u16* __restrict__ A, const u16* __restrict__ Bt,
    const void* __restrict__ bias, int bias_bf, void* __restrict__ Cout, int mode,
    float cscale) {
  constexpr int MI = MT / 32;                             // acc row-tiles per wave
  __shared__ __align__(16) u16 As[2][MT * 32];
  __shared__ __align__(16) u16 Bs[2][128 * 32];
  const int tid = threadIdx.x;
  const int wave = tid >> 6, lane = tid & 63;
  const int qd = lane >> 4, ln = lane & 15;
  const int m0 = blockIdx.y * MT, n0 = blockIdx.x * 128;
  const int wr = (wave >> 1) * (MT / 2), wc = (wave & 1) * 64;
  const int r0 = wave * 16 + (lane >> 2);
  const int csrc = ((lane & 3) ^ ((lane >> 2) & 3)) * 8;  // swizzled src chunk
  const u16* Ag = &A[(size_t)m0 * 1024];
  const u16* Bg = &Bt[(size_t)n0 * 1024];
  const int co = (qd ^ (ln & 3)) * 8;                     // frag-read chunk
  f4v acc[MI][4];
#pragma unroll
  for (int i = 0; i < MI; ++i)
#pragma unroll
    for (int j = 0; j < 4; ++j) acc[i][j] = (f4v){0.f, 0.f, 0.f, 0.f};

#pragma unroll
  for (int t = 0; t < MT / 64; ++t)
    cp16(&Ag[(size_t)(t * 64 + r0) * 1024 + csrc], &As[0][(t * 256 + wave * 64) * 8]);
#pragma unroll
  for (int t = 0; t < 2; ++t)
    cp16(&Bg[(size_t)(t * 64 + r0) * 1024 + csrc], &Bs[0][(t * 256 + wave * 64) * 8]);

  for (int it = 0; it < 32; ++it) {
    __syncthreads();                       // drains stage(it) (issued last iter)
    if (it < 31) {
      int ko = (it + 1) * 32;
      int bi = (it + 1) & 1;
#pragma unroll
      for (int t = 0; t < MT / 64; ++t)
        cp16(&Ag[(size_t)(t * 64 + r0) * 1024 + ko + csrc], &As[bi][(t * 256 + wave * 64) * 8]);
#pragma unroll
      for (int t = 0; t < 2; ++t)
        cp16(&Bg[(size_t)(t * 64 + r0) * 1024 + ko + csrc], &Bs[bi][(t * 256 + wave * 64) * 8]);
    }
    const u16* as = As[it & 1];
    const u16* bs = Bs[it & 1];
    bf8v af[MI], bfr[4];
#pragma unroll
    for (int i = 0; i < MI; ++i) af[i]  = *(const bf8v*)&as[(wr + i * 16 + ln) * 32 + co];
#pragma unroll
    for (int j = 0; j < 4; ++j) bfr[j] = *(const bf8v*)&bs[(wc + j * 16 + ln) * 32 + co];
#pragma unroll
    for (int i = 0; i < MI; ++i)
#pragma unroll
      for (int j = 0; j < 4; ++j)
        acc[i][j] = __builtin_amdgcn_mfma_f32_16x16x32_bf16(af[i], bfr[j], acc[i][j], 0, 0, 0);
  }
  // epilogue: C row = m0+wr+i*16+qd*4+r, col = n0+wc+j*16+ln
#pragma unroll
  for (int j = 0; j < 4; ++j) {
    int col = n0 + wc + j * 16 + ln;
    float bv = bias_bf ? bf2f(((const u16*)bias)[col]) : ((const float*)bias)[col];
#pragma unroll
    for (int i = 0; i < MI; ++i) {
      int row = m0 + wr + i * 16 + qd * 4;
      if (mode == 2) {
        // scatter to vF[bh][kt][c][dt][lane(qd_f*16+ln_f)][8]
        ushort4 o4;
        o4.x = f2bf((acc[i][j][0] + bv) * cscale);
        o4.y = f2bf((acc[i][j][1] + bv) * cscale);
        o4.z = f2bf((acc[i][j][2] + bv) * cscale);
        o4.w = f2bf((acc[i][j][3] + bv) * cscale);
        int b_ = row >> 11, nl = row & 2047;
        int h_ = col >> 6, d6 = col & 63;
        int kt = nl >> 6, b0 = nl & 63;
        int c = b0 >> 5, g = (b0 >> 4) & 1, qd_f = (b0 >> 2) & 3;
        int dt = d6 >> 4, ln_f = d6 & 15;
        size_t off = (size_t)(b_ * 16 + h_) * 131072
                   + (size_t)(kt * 4096 + (c * 4 + dt) * 512 + (qd_f * 16 + ln_f) * 8 + g * 4);
        *(ushort4*)&((u16*)Cout)[off] = o4;
      } else {
#pragma unroll
        for (int r = 0; r < 4; ++r) {
          float v = (acc[i][j][r] + bv) * cscale;
          if (mode == 1) ((u16*)Cout)[(size_t)(row + r) * 1024 + col] = f2bf(v);
          else           ((float*)Cout)[(size_t)(row + r) * 1024 + col] = v;
        }
      }
    }
  }
}

__global__ __launch_bounds__(256) void k_gemm_qkv(const u16* xb, const u16* wt,
    const void* bq, const void* bk, const void* bv, const int* flags,
    u16* qpre, u16* kb, u16* vtb) {
  int z = blockIdx.z;
  const u16* Bt = wt + (size_t)z * (1u << 20);
  const void* bias = (z == 0) ? bq : (z == 1) ? bk : bv;
  if (z == 0)      gemm_bt<128>(xb, Bt, bias, flags[2], qpre, 1, 1.0f);
  else if (z == 1) gemm_bt<128>(xb, Bt, bias, flags[4], kb,   1, KSCALE);
  else             gemm_bt<128>(xb, Bt, bias, flags[6], vtb,  2, 1.0f);
}

__global__ __launch_bounds__(256) void k_gemm_out(const u16* A, const u16* Bt,
    const void* bias, const int* flags, void* out) {
  gemm_bt<64>(A, Bt, bias, flags[8], out, flags[0] ? 1 : 0, 1.0f);
}

// ---------------------------------------------------------------------------
// LayerNorm over rows of 1024: block per row, 256 threads x 4 elems.
// ---------------------------------------------------------------------------
__global__ __launch_bounds__(256) void k_layernorm(const u16* __restrict__ qp,
    const void* __restrict__ g, const void* __restrict__ bb, const int* flags,
    u16* __restrict__ out) {
  int row = blockIdx.x, t = threadIdx.x;
  const u16* rp = qp + (size_t)row * 1024;
  ushort4 u = *(const ushort4*)(rp + t * 4);
  float x0 = bf2f(u.x), x1 = bf2f(u.y), x2 = bf2f(u.z), x3 = bf2f(u.w);
  float s = x0 + x1 + x2 + x3;
  float s2 = x0 * x0 + x1 * x1 + x2 * x2 + x3 * x3;
  for (int off = 32; off; off >>= 1) { s += __shfl_down(s, off); s2 += __shfl_down(s2, off); }
  __shared__ float red[10];
  int wave = t >> 6, lane = t & 63;
  if (lane == 0) { red[wave] = s; red[4 + wave] = s2; }
  __syncthreads();
  if (t == 0) {
    float S = red[0] + red[1] + red[2] + red[3];
    float S2 = red[4] + red[5] + red[6] + red[7];
    float mu = S * (1.f / 1024.f);
    float var = S2 * (1.f / 1024.f) - mu * mu;
    red[8] = mu; red[9] = rsqrtf(var + 1e-5f);
  }
  __syncthreads();
  float mu = red[8], rstd = red[9];
  int gf = flags[9], bf = flags[10];
  int c = t * 4;
  float gv[4], bv[4];
#pragma unroll
  for (int k = 0; k < 4; ++k) {
    gv[k] = gf ? bf2f(((const u16*)g)[c + k]) : ((const float*)g)[c + k];
    bv[k] = bf ? bf2f(((const u16*)bb)[c + k]) : ((const float*)bb)[c + k];
  }
  ushort4 o;
  o.x = f2bf((x0 - mu) * rstd * gv[0] + bv[0]);
  o.y = f2bf((x1 - mu) * rstd * gv[1] + bv[1]);
  o.z = f2bf((x2 - mu) * rstd * gv[2] + bv[2]);
  o.w = f2bf((x3 - mu) * rstd * gv[3] + bv[3]);
  *(ushort4*)(out + (size_t)row * 1024 + c) = o;
}

// ---------------------------------------------------------------------------
// Flash attention: LDS-free, BARRIER-FREE, one wave per block (64 threads).
// 32 q-rows per wave (2 subtiles of 16) x all 2048 keys in 64-key tiles;
// grid 2048 (q split across blocks -> 8 blocks/CU of work vs R9's 4).
// Per iter: 8 K-frag + 8 V-frag global dwordx4 loads feed 32 MFMA; no
// __syncthreads anywhere -> compiler pipelines loads across iters on vmcnt.
// K natural layout (64B-coalesced); V fragment-ordered vF (1KB coalesced).
// S^T = mfma(K,Q), scale pre-folded in K; P packed bf16 (v_perm) = PV A-frag.
// XCD-swizzled decode (x&7) keeps each (b,h)'s K/V in one XCD's L2.
// Residual (+q_ln) fused into the store.
// ---------------------------------------------------------------------------
__global__ __launch_bounds__(64) void k_attention(const u16* __restrict__ qln,
    const u16* __restrict__ kb, const u16* __restrict__ vfg, u16* __restrict__ attn) {
  const int x = blockIdx.x;
  const int xcd = x & 7, sl = x >> 3;                // sl in [0,256)
  const int bh = xcd * 4 + (sl >> 6), qt = sl & 63;  // 4 bh per XCD group, 64 q-tiles
  const int b = bh >> 4, h = bh & 15;
  const int lane = threadIdx.x;
  const int qd = lane >> 4, ln = lane & 15;
  const int qrow0 = qt * 32;

  const u16* kgb = kb + (size_t)b * 2048 * 1024 + h * 64;
  const u16* vgb = vfg + (size_t)bh * 131072;

  bf8v qf[2][2];
#pragma unroll
  for (int qs = 0; qs < 2; ++qs) {
    const u16* qb = qln + ((size_t)b * 2048 + qrow0 + qs * 16 + ln) * 1024 + h * 64;
    qf[qs][0] = *(const bf8v*)(qb + qd * 8);
    qf[qs][1] = *(const bf8v*)(qb + 32 + qd * 8);
  }
  float ls[2][4];
  f4v o[2][4];
#pragma unroll
  for (int qs = 0; qs < 2; ++qs)
#pragma unroll
    for (int r = 0; r < 4; ++r) { ls[qs][r] = 0.f; o[qs][r] = (f4v){0.f, 0.f, 0.f, 0.f}; }

  for (int kt = 0; kt < 2048; kt += 64) {
    // K-frags: natural layout, lane (qd,ln) reads 16B of row ct*16+ln
    const u16* kr = kgb + (size_t)kt * 1024;
    bf8v kf[4][2];
#pragma unroll
    for (int ct = 0; ct < 4; ++ct) {
      kf[ct][0] = *(const bf8v*)(kr + (size_t)(ct * 16 + ln) * 1024 + qd * 8);
      kf[ct][1] = *(const bf8v*)(kr + (size_t)(ct * 16 + ln) * 1024 + 32 + qd * 8);
    }
    // V-frags: fragment-ordered, fully coalesced (512 elems per [c][dt] chunk)
    const u16* vr = vgb + (size_t)(kt >> 6) * 4096;
    bf8v vf[8];
#pragma unroll
    for (int cd = 0; cd < 8; ++cd)
      vf[cd] = *(const bf8v*)(vr + cd * 512 + lane * 8);

#pragma unroll
    for (int qs = 0; qs < 2; ++qs) {
      unsigned pk[4][2];
#pragma unroll
      for (int ct = 0; ct < 4; ++ct) {
        f4v z = (f4v){0.f, 0.f, 0.f, 0.f};
        z = __builtin_amdgcn_mfma_f32_16x16x32_bf16(kf[ct][0], qf[qs][0], z, 0, 0, 0);  // S^T
        z = __builtin_amdgcn_mfma_f32_16x16x32_bf16(kf[ct][1], qf[qs][1], z, 0, 0, 0);
        float p0 = __builtin_amdgcn_exp2f(z[0]);
        float p1 = __builtin_amdgcn_exp2f(z[1]);
        float p2 = __builtin_amdgcn_exp2f(z[2]);
        float p3 = __builtin_amdgcn_exp2f(z[3]);
        ls[qs][0] += p0; ls[qs][1] += p1; ls[qs][2] += p2; ls[qs][3] += p3;
        pk[ct][0] = pack2bf(p0, p1);
        pk[ct][1] = pack2bf(p2, p3);
      }
#pragma unroll
      for (int c = 0; c < 2; ++c) {
        unsigned avals[4] = {pk[2*c][0], pk[2*c][1], pk[2*c+1][0], pk[2*c+1][1]};
        bf8v af; __builtin_memcpy(&af, avals, 16);
#pragma unroll
        for (int dt = 0; dt < 4; ++dt)
          o[qs][dt] = __builtin_amdgcn_mfma_f32_16x16x32_bf16(af, vf[c * 4 + dt], o[qs][dt], 0, 0, 0);
      }
    }
  }
  // per q-subtile: reduce den (2 shuffles), store with fused residual
#pragma unroll
  for (int qs = 0; qs < 2; ++qs) {
    float lsum = (ls[qs][0] + ls[qs][1]) + (ls[qs][2] + ls[qs][3]);
    lsum += __shfl_xor(lsum, 16);
    lsum += __shfl_xor(lsum, 32);                     // den[q=ln] on every lane
    float rden[4];
#pragma unroll
    for (int r = 0; r < 4; ++r) {
      float dv = __shfl(lsum, (lane & 48) + qd * 4 + r);  // lane with ln=qd*4+r
      rden[r] = __builtin_amdgcn_rcpf(1e-8f + dv);
    }
#pragma unroll
    for (int dt = 0; dt < 4; ++dt) {
#pragma unroll
      for (int r = 0; r < 4; ++r) {
        size_t idx = ((size_t)b * 2048 + qrow0 + qs * 16 + qd * 4 + r) * 1024
                   + h * 64 + dt * 16 + ln;
        float val = o[qs][dt][r] * rden[r] + bf2f(qln[idx]);
        attn[idx] = f2bf(val);
      }
    }
  }
}

// ---------------------------------------------------------------------------
extern "C" void kernel_launch(void* const* d_in, const int* in_sizes, int n_in,
                              void* d_out, int out_size, void* d_ws, size_t ws_size,
                              hipStream_t stream) {
  // inputs: 0:x 1:Wq 2:bq 3:Wk 4:bk 5:Wv 6:bv 7:Wo 8:bo 9:ln_g 10:ln_b
  int* flags = (int*)d_ws;
  u16* base = (u16*)((char*)d_ws + 256);
  const size_t M1 = 1u << 20;
  u16* xb   = base;            // x bf16; overwritten by qln after gemm_qkv
  u16* wt   = base + 4 * M1;   // Wq^T,Wk^T,Wv^T,Wo^T (4 x 1M)
  u16* qpre = base + 8 * M1;   // q pre-LN; reused as attn-out after LN
  u16* kb   = base + 12 * M1;  // K (pre-scaled by KSCALE)
  u16* vtb  = base + 16 * M1;  // vF fragment-ordered V (written by V-GEMM)
  u16* qln = xb;
  u16* at  = qpre;

  k_classify<<<1, 64, 0, stream>>>(
      (const u16*)d_in[0], (const u16*)d_in[1], (const u16*)d_in[2], (const u16*)d_in[3],
      (const u16*)d_in[4], (const u16*)d_in[5], (const u16*)d_in[6], (const u16*)d_in[7],
      (const u16*)d_in[8], (const u16*)d_in[9], (const u16*)d_in[10], flags);

  k_convert_x<<<2048, 256, 0, stream>>>(d_in[0], xb, flags);
  k_transpose_w<<<dim3(16, 16, 4), 256, 0, stream>>>(d_in[1], d_in[3], d_in[5], d_in[7], wt, flags);
  k_gemm_qkv<<<dim3(8, 32, 3), 256, 0, stream>>>(xb, wt, d_in[2], d_in[4], d_in[6], flags,
                                                 qpre, kb, vtb);
  k_layernorm<<<4096, 256, 0, stream>>>(qpre, d_in[9], d_in[10], flags, qln);
  k_attention<<<2048, 64, 0, stream>>>(qln, kb, vtb, at);
  k_gemm_out<<<dim3(8, 64), 256, 0, stream>>>(at, wt + 3 * M1, d_in[8], flags, d_out);
}

// Round 12
// 227.976 us; speedup vs baseline: 1.1230x; 1.1230x over previous
//
#include <hip/hip_runtime.h>

// ============================================================================
// EfficientAttention: x->(QKV proj)->LN(q)->flash attention->(+q)->out proj
// B=2, N=2048, D=1024, H=16, d=64.  bf16 MFMA pipeline, fp32 accumulate.
// R12: attention = R9's LDS-free barrier-free per-wave body (64 q-rows/wave,
//      direct global->VGPR K/V frags), but blocks are 4 waves covering 256
//      q-rows that MARCH THE SAME K/V TILE SEQUENCE: co-resident same-address
//      loads dedupe in L1/MSHR, so unique L2 traffic drops 4x vs R9 (128 MB)
//      at unchanged per-wave compute. Grid 256 = 32 bh x 8 q-chunks,
//      XCD-swizzled. (R11's q-split doubled traffic and regressed — the
//      binding resource is the K/V stream, not wave count.)
// ============================================================================

typedef unsigned short u16;
typedef __attribute__((ext_vector_type(8))) short bf8v;   // 8 bf16 (bit-pattern shorts)
typedef __attribute__((ext_vector_type(4))) float f4v;    // MFMA acc

typedef __attribute__((address_space(1))) void gvoid;
typedef __attribute__((address_space(3))) void lvoid;
__device__ __forceinline__ void cp16(const void* g, void* l) {
  __builtin_amdgcn_global_load_lds((gvoid*)g, (lvoid*)l, 16, 0, 0);
}

__device__ __forceinline__ float bf2f(u16 u) {
  unsigned int x = ((unsigned int)u) << 16;
  float f; __builtin_memcpy(&f, &x, 4); return f;
}
__device__ __forceinline__ u16 f2bf(float f) {
  unsigned int x; __builtin_memcpy(&x, &f, 4);
  unsigned int r = (x + 0x7fffu + ((x >> 16) & 1u)) >> 16;   // RNE
  return (u16)r;
}
// pack 2 floats' bf16 truncations into one u32 (a -> low16, b -> high16)
__device__ __forceinline__ unsigned pack2bf(float a, float b) {
  unsigned ua, ub;
  __builtin_memcpy(&ua, &a, 4); __builtin_memcpy(&ub, &b, 4);
  return __builtin_amdgcn_perm(ub, ua, 0x07060302u);
}

#define KSCALE 0.18033688011f   // log2(e) / sqrt(64)

// ---------------------------------------------------------------------------
// dtype classifier: flags[t]=1 if tensor t looks like bf16, 0 if fp32.
// ---------------------------------------------------------------------------
__global__ void k_classify(const u16* a0, const u16* a1, const u16* a2, const u16* a3,
                           const u16* a4, const u16* a5, const u16* a6, const u16* a7,
                           const u16* a8, const u16* a9, const u16* a10, int* flags) {
  int t = threadIdx.x;
  if (t >= 11) return;
  const u16* arr[11] = {a0,a1,a2,a3,a4,a5,a6,a7,a8,a9,a10};
  const u16* p = arr[t];
  int ze = 0, no = 0, pe = 0;
  for (int i = 0; i < 128; ++i) {
    u16 he = p[2*i], ho = p[2*i+1];
    if (he == 0) ze++;
    if (ho != 0) no++;
    int e = (he >> 7) & 0xff;
    if (he == 0 || (e >= 64 && e <= 160)) pe++;
  }
  int isbf;
  if (ze >= 100 && no >= 64) isbf = 0;          // fp32 clean constants
  else isbf = (pe >= 100) ? 1 : 0;
  flags[t] = isbf;
}

// x (4M elems) -> bf16 ws copy, 8 elems/thread
__global__ __launch_bounds__(256) void k_convert_x(const void* xin, u16* xb, const int* flags) {
  size_t i = ((size_t)blockIdx.x * 256 + threadIdx.x) * 8;
  if (flags[0]) {
    *(float4*)(xb + i) = *((const float4*)((const u16*)xin + i));
  } else {
    const float* xf = (const float*)xin;
    float4 a = *(const float4*)(xf + i);
    float4 b = *(const float4*)(xf + i + 4);
    ushort4 o0, o1;
    o0.x = f2bf(a.x); o0.y = f2bf(a.y); o0.z = f2bf(a.z); o0.w = f2bf(a.w);
    o1.x = f2bf(b.x); o1.y = f2bf(b.y); o1.z = f2bf(b.z); o1.w = f2bf(b.w);
    *(ushort4*)(xb + i) = o0; *(ushort4*)(xb + i + 4) = o1;
  }
}

// W[k][n] (1024x1024) -> Wt[n][k] bf16, LDS 64x64 tile (pad 65 => 2-way banks)
__global__ __launch_bounds__(256) void k_transpose_w(const void* W0, const void* W1,
    const void* W2, const void* W3, u16* wt, const int* flags) {
  __shared__ u16 tile[64 * 65];
  int z = blockIdx.z;
  const void* W = (z == 0) ? W0 : (z == 1) ? W1 : (z == 2) ? W2 : W3;
  int isb = flags[1 + 2*z];
  u16* dst = wt + (size_t)z * (1u << 20);
  int r0 = blockIdx.y * 64, c0 = blockIdx.x * 64;
  int t = threadIdx.x;
  for (int rr = 0; rr < 2; ++rr) {
    int row = rr * 32 + (t >> 3);
    int c8 = (t & 7) * 8;
    u16 v[8];
    if (isb) {
      const u16* Ws = (const u16*)W;
      ushort4 a = *(const ushort4*)&Ws[(size_t)(r0 + row) * 1024 + c0 + c8];
      ushort4 b = *(const ushort4*)&Ws[(size_t)(r0 + row) * 1024 + c0 + c8 + 4];
      v[0]=a.x; v[1]=a.y; v[2]=a.z; v[3]=a.w; v[4]=b.x; v[5]=b.y; v[6]=b.z; v[7]=b.w;
    } else {
      const float* Wf = (const float*)W;
      float4 a = *(const float4*)&Wf[(size_t)(r0 + row) * 1024 + c0 + c8];
      float4 b = *(const float4*)&Wf[(size_t)(r0 + row) * 1024 + c0 + c8 + 4];
      v[0]=f2bf(a.x); v[1]=f2bf(a.y); v[2]=f2bf(a.z); v[3]=f2bf(a.w);
      v[4]=f2bf(b.x); v[5]=f2bf(b.y); v[6]=f2bf(b.z); v[7]=f2bf(b.w);
    }
#pragma unroll
    for (int j = 0; j < 8; ++j) tile[row * 65 + c8 + j] = v[j];
  }
  __syncthreads();
  for (int rr = 0; rr < 2; ++rr) {
    int nrow = rr * 32 + (t >> 3);
    int k8 = (t & 7) * 8;
    u16 v[8];
#pragma unroll
    for (int j = 0; j < 8; ++j) v[j] = tile[(k8 + j) * 65 + nrow];
    ushort4 o0, o1;
    o0.x=v[0]; o0.y=v[1]; o0.z=v[2]; o0.w=v[3];
    o1.x=v[4]; o1.y=v[5]; o1.z=v[6]; o1.w=v[7];
    *(ushort4*)&dst[(size_t)(c0 + nrow) * 1024 + r0 + k8] = o0;
    *(ushort4*)&dst[(size_t)(c0 + nrow) * 1024 + r0 + k8 + 4] = o1;
  }
}

// ---------------------------------------------------------------------------
// MTx128-tile gemm_bt: C[M,1024] = A[M,1024] @ Bt[1024,1024]^T + bias
// BK=32, double-buffered LDS, ONE barrier per K-iter.
// mode: 0 = fp32 rowmajor, 1 = bf16 rowmajor, 2 = bf16 scatter to vF
// ---------------------------------------------------------------------------
template <int MT>
__device__ __forceinline__ void gemm_bt(const u16* __restrict__ A, const u16* __restrict__ Bt,
    const void* __restrict__ bias, int bias_bf, void* __restrict__ Cout, int mode,
    float cscale) {
  constexpr int MI = MT / 32;                             // acc row-tiles per wave
  __shared__ __align__(16) u16 As[2][MT * 32];
  __shared__ __align__(16) u16 Bs[2][128 * 32];
  const int tid = threadIdx.x;
  const int wave = tid >> 6, lane = tid & 63;
  const int qd = lane >> 4, ln = lane & 15;
  const int m0 = blockIdx.y * MT, n0 = blockIdx.x * 128;
  const int wr = (wave >> 1) * (MT / 2), wc = (wave & 1) * 64;
  const int r0 = wave * 16 + (lane >> 2);
  const int csrc = ((lane & 3) ^ ((lane >> 2) & 3)) * 8;  // swizzled src chunk
  const u16* Ag = &A[(size_t)m0 * 1024];
  const u16* Bg = &Bt[(size_t)n0 * 1024];
  const int co = (qd ^ (ln & 3)) * 8;                     // frag-read chunk
  f4v acc[MI][4];
#pragma unroll
  for (int i = 0; i < MI; ++i)
#pragma unroll
    for (int j = 0; j < 4; ++j) acc[i][j] = (f4v){0.f, 0.f, 0.f, 0.f};

#pragma unroll
  for (int t = 0; t < MT / 64; ++t)
    cp16(&Ag[(size_t)(t * 64 + r0) * 1024 + csrc], &As[0][(t * 256 + wave * 64) * 8]);
#pragma unroll
  for (int t = 0; t < 2; ++t)
    cp16(&Bg[(size_t)(t * 64 + r0) * 1024 + csrc], &Bs[0][(t * 256 + wave * 64) * 8]);

  for (int it = 0; it < 32; ++it) {
    __syncthreads();                       // drains stage(it) (issued last iter)
    if (it < 31) {
      int ko = (it + 1) * 32;
      int bi = (it + 1) & 1;
#pragma unroll
      for (int t = 0; t < MT / 64; ++t)
        cp16(&Ag[(size_t)(t * 64 + r0) * 1024 + ko + csrc], &As[bi][(t * 256 + wave * 64) * 8]);
#pragma unroll
      for (int t = 0; t < 2; ++t)
        cp16(&Bg[(size_t)(t * 64 + r0) * 1024 + ko + csrc], &Bs[bi][(t * 256 + wave * 64) * 8]);
    }
    const u16* as = As[it & 1];
    const u16* bs = Bs[it & 1];
    bf8v af[MI], bfr[4];
#pragma unroll
    for (int i = 0; i < MI; ++i) af[i]  = *(const bf8v*)&as[(wr + i * 16 + ln) * 32 + co];
#pragma unroll
    for (int j = 0; j < 4; ++j) bfr[j] = *(const bf8v*)&bs[(wc + j * 16 + ln) * 32 + co];
#pragma unroll
    for (int i = 0; i < MI; ++i)
#pragma unroll
      for (int j = 0; j < 4; ++j)
        acc[i][j] = __builtin_amdgcn_mfma_f32_16x16x32_bf16(af[i], bfr[j], acc[i][j], 0, 0, 0);
  }
  // epilogue: C row = m0+wr+i*16+qd*4+r, col = n0+wc+j*16+ln
#pragma unroll
  for (int j = 0; j < 4; ++j) {
    int col = n0 + wc + j * 16 + ln;
    float bv = bias_bf ? bf2f(((const u16*)bias)[col]) : ((const float*)bias)[col];
#pragma unroll
    for (int i = 0; i < MI; ++i) {
      int row = m0 + wr + i * 16 + qd * 4;
      if (mode == 2) {
        // scatter to vF[bh][kt][c][dt][lane(qd_f*16+ln_f)][8]
        ushort4 o4;
        o4.x = f2bf((acc[i][j][0] + bv) * cscale);
        o4.y = f2bf((acc[i][j][1] + bv) * cscale);
        o4.z = f2bf((acc[i][j][2] + bv) * cscale);
        o4.w = f2bf((acc[i][j][3] + bv) * cscale);
        int b_ = row >> 11, nl = row & 2047;
        int h_ = col >> 6, d6 = col & 63;
        int kt = nl >> 6, b0 = nl & 63;
        int c = b0 >> 5, g = (b0 >> 4) & 1, qd_f = (b0 >> 2) & 3;
        int dt = d6 >> 4, ln_f = d6 & 15;
        size_t off = (size_t)(b_ * 16 + h_) * 131072
                   + (size_t)(kt * 4096 + (c * 4 + dt) * 512 + (qd_f * 16 + ln_f) * 8 + g * 4);
        *(ushort4*)&((u16*)Cout)[off] = o4;
      } else {
#pragma unroll
        for (int r = 0; r < 4; ++r) {
          float v = (acc[i][j][r] + bv) * cscale;
          if (mode == 1) ((u16*)Cout)[(size_t)(row + r) * 1024 + col] = f2bf(v);
          else           ((float*)Cout)[(size_t)(row + r) * 1024 + col] = v;
        }
      }
    }
  }
}

__global__ __launch_bounds__(256) void k_gemm_qkv(const u16* xb, const u16* wt,
    const void* bq, const void* bk, const void* bv, const int* flags,
    u16* qpre, u16* kb, u16* vtb) {
  int z = blockIdx.z;
  const u16* Bt = wt + (size_t)z * (1u << 20);
  const void* bias = (z == 0) ? bq : (z == 1) ? bk : bv;
  if (z == 0)      gemm_bt<128>(xb, Bt, bias, flags[2], qpre, 1, 1.0f);
  else if (z == 1) gemm_bt<128>(xb, Bt, bias, flags[4], kb,   1, KSCALE);
  else             gemm_bt<128>(xb, Bt, bias, flags[6], vtb,  2, 1.0f);
}

__global__ __launch_bounds__(256) void k_gemm_out(const u16* A, const u16* Bt,
    const void* bias, const int* flags, void* out) {
  gemm_bt<64>(A, Bt, bias, flags[8], out, flags[0] ? 1 : 0, 1.0f);
}

// ---------------------------------------------------------------------------
// LayerNorm over rows of 1024: block per row, 256 threads x 4 elems.
// ---------------------------------------------------------------------------
__global__ __launch_bounds__(256) void k_layernorm(const u16* __restrict__ qp,
    const void* __restrict__ g, const void* __restrict__ bb, const int* flags,
    u16* __restrict__ out) {
  int row = blockIdx.x, t = threadIdx.x;
  const u16* rp = qp + (size_t)row * 1024;
  ushort4 u = *(const ushort4*)(rp + t * 4);
  float x0 = bf2f(u.x), x1 = bf2f(u.y), x2 = bf2f(u.z), x3 = bf2f(u.w);
  float s = x0 + x1 + x2 + x3;
  float s2 = x0 * x0 + x1 * x1 + x2 * x2 + x3 * x3;
  for (int off = 32; off; off >>= 1) { s += __shfl_down(s, off); s2 += __shfl_down(s2, off); }
  __shared__ float red[10];
  int wave = t >> 6, lane = t & 63;
  if (lane == 0) { red[wave] = s; red[4 + wave] = s2; }
  __syncthreads();
  if (t == 0) {
    float S = red[0] + red[1] + red[2] + red[3];
    float S2 = red[4] + red[5] + red[6] + red[7];
    float mu = S * (1.f / 1024.f);
    float var = S2 * (1.f / 1024.f) - mu * mu;
    red[8] = mu; red[9] = rsqrtf(var + 1e-5f);
  }
  __syncthreads();
  float mu = red[8], rstd = red[9];
  int gf = flags[9], bf = flags[10];
  int c = t * 4;
  float gv[4], bv[4];
#pragma unroll
  for (int k = 0; k < 4; ++k) {
    gv[k] = gf ? bf2f(((const u16*)g)[c + k]) : ((const float*)g)[c + k];
    bv[k] = bf ? bf2f(((const u16*)bb)[c + k]) : ((const float*)bb)[c + k];
  }
  ushort4 o;
  o.x = f2bf((x0 - mu) * rstd * gv[0] + bv[0]);
  o.y = f2bf((x1 - mu) * rstd * gv[1] + bv[1]);
  o.z = f2bf((x2 - mu) * rstd * gv[2] + bv[2]);
  o.w = f2bf((x3 - mu) * rstd * gv[3] + bv[3]);
  *(ushort4*)(out + (size_t)row * 1024 + c) = o;
}

// ---------------------------------------------------------------------------
// Flash attention: LDS-free, BARRIER-FREE. 256-thread blocks (4 waves), each
// wave 64 q-rows (4 subtiles of 16); ALL 4 WAVES MARCH THE SAME K/V TILE
// SEQUENCE so co-resident same-address loads dedupe in L1/MSHR -> unique L2
// traffic = 256 blocks x 512 KB = 128 MB (4x less than R9, 8x less than R11).
// Per iter per wave: 8 K-frag + 8 V-frag global dwordx4 loads feed 64 MFMA.
// K natural layout (64B-coalesced); V fragment-ordered vF (1KB coalesced).
// S^T = mfma(K,Q), scale pre-folded in K; P packed bf16 (v_perm) = PV A-frag.
// Grid 256 = XCD slot (x&7) x 4 bh x 8 q-chunks; residual fused into store.
// ---------------------------------------------------------------------------
__global__ __launch_bounds__(256) void k_attention(const u16* __restrict__ qln,
    const u16* __restrict__ kb, const u16* __restrict__ vfg, u16* __restrict__ attn) {
  const int x = blockIdx.x;
  const int xcd = x & 7, sl = x >> 3;                // sl in [0,32)
  const int bh = xcd * 4 + (sl >> 3), qc = sl & 7;   // 4 bh per XCD slot, 8 q-chunks
  const int b = bh >> 4, h = bh & 15;
  const int tid = threadIdx.x, wave = tid >> 6, lane = tid & 63;
  const int qd = lane >> 4, ln = lane & 15;
  const int qrow0 = qc * 256 + wave * 64;            // this wave's 64 q-rows

  const u16* kgb = kb + (size_t)b * 2048 * 1024 + h * 64;
  const u16* vgb = vfg + (size_t)bh * 131072;

  bf8v qf[4][2];
#pragma unroll
  for (int qs = 0; qs < 4; ++qs) {
    const u16* qb = qln + ((size_t)b * 2048 + qrow0 + qs * 16 + ln) * 1024 + h * 64;
    qf[qs][0] = *(const bf8v*)(qb + qd * 8);
    qf[qs][1] = *(const bf8v*)(qb + 32 + qd * 8);
  }
  float ls[4][4];
  f4v o[4][4];
#pragma unroll
  for (int qs = 0; qs < 4; ++qs)
#pragma unroll
    for (int r = 0; r < 4; ++r) { ls[qs][r] = 0.f; o[qs][r] = (f4v){0.f, 0.f, 0.f, 0.f}; }

  for (int kt = 0; kt < 2048; kt += 64) {
    // K-frags: natural layout, lane (qd,ln) reads 16B of row ct*16+ln
    const u16* kr = kgb + (size_t)kt * 1024;
    bf8v kf[4][2];
#pragma unroll
    for (int ct = 0; ct < 4; ++ct) {
      kf[ct][0] = *(const bf8v*)(kr + (size_t)(ct * 16 + ln) * 1024 + qd * 8);
      kf[ct][1] = *(const bf8v*)(kr + (size_t)(ct * 16 + ln) * 1024 + 32 + qd * 8);
    }
    // V-frags: fragment-ordered, fully coalesced (512 elems per [c][dt] chunk)
    const u16* vr = vgb + (size_t)(kt >> 6) * 4096;
    bf8v vf[8];
#pragma unroll
    for (int cd = 0; cd < 8; ++cd)
      vf[cd] = *(const bf8v*)(vr + cd * 512 + lane * 8);

#pragma unroll
    for (int qs = 0; qs < 4; ++qs) {
      unsigned pk[4][2];
#pragma unroll
      for (int ct = 0; ct < 4; ++ct) {
        f4v z = (f4v){0.f, 0.f, 0.f, 0.f};
        z = __builtin_amdgcn_mfma_f32_16x16x32_bf16(kf[ct][0], qf[qs][0], z, 0, 0, 0);  // S^T
        z = __builtin_amdgcn_mfma_f32_16x16x32_bf16(kf[ct][1], qf[qs][1], z, 0, 0, 0);
        float p0 = __builtin_amdgcn_exp2f(z[0]);
        float p1 = __builtin_amdgcn_exp2f(z[1]);
        float p2 = __builtin_amdgcn_exp2f(z[2]);
        float p3 = __builtin_amdgcn_exp2f(z[3]);
        ls[qs][0] += p0; ls[qs][1] += p1; ls[qs][2] += p2; ls[qs][3] += p3;
        pk[ct][0] = pack2bf(p0, p1);
        pk[ct][1] = pack2bf(p2, p3);
      }
#pragma unroll
      for (int c = 0; c < 2; ++c) {
        unsigned avals[4] = {pk[2*c][0], pk[2*c][1], pk[2*c+1][0], pk[2*c+1][1]};
        bf8v af; __builtin_memcpy(&af, avals, 16);
#pragma unroll
        for (int dt = 0; dt < 4; ++dt)
          o[qs][dt] = __builtin_amdgcn_mfma_f32_16x16x32_bf16(af, vf[c * 4 + dt], o[qs][dt], 0, 0, 0);
      }
    }
  }
  // per q-subtile: reduce den (2 shuffles), store with fused residual
#pragma unroll
  for (int qs = 0; qs < 4; ++qs) {
    float lsum = (ls[qs][0] + ls[qs][1]) + (ls[qs][2] + ls[qs][3]);
    lsum += __shfl_xor(lsum, 16);
    lsum += __shfl_xor(lsum, 32);                     // den[q=ln] on every lane
    float rden[4];
#pragma unroll
    for (int r = 0; r < 4; ++r) {
      float dv = __shfl(lsum, (lane & 48) + qd * 4 + r);  // lane with ln=qd*4+r
      rden[r] = __builtin_amdgcn_rcpf(1e-8f + dv);
    }
#pragma unroll
    for (int dt = 0; dt < 4; ++dt) {
#pragma unroll
      for (int r = 0; r < 4; ++r) {
        size_t idx = ((size_t)b * 2048 + qrow0 + qs * 16 + qd * 4 + r) * 1024
                   + h * 64 + dt * 16 + ln;
        float val = o[qs][dt][r] * rden[r] + bf2f(qln[idx]);
        attn[idx] = f2bf(val);
      }
    }
  }
}

// ---------------------------------------------------------------------------
extern "C" void kernel_launch(void* const* d_in, const int* in_sizes, int n_in,
                              void* d_out, int out_size, void* d_ws, size_t ws_size,
                              hipStream_t stream) {
  // inputs: 0:x 1:Wq 2:bq 3:Wk 4:bk 5:Wv 6:bv 7:Wo 8:bo 9:ln_g 10:ln_b
  int* flags = (int*)d_ws;
  u16* base = (u16*)((char*)d_ws + 256);
  const size_t M1 = 1u << 20;
  u16* xb   = base;            // x bf16; overwritten by qln after gemm_qkv
  u16* wt   = base + 4 * M1;   // Wq^T,Wk^T,Wv^T,Wo^T (4 x 1M)
  u16* qpre = base + 8 * M1;   // q pre-LN; reused as attn-out after LN
  u16* kb   = base + 12 * M1;  // K (pre-scaled by KSCALE)
  u16* vtb  = base + 16 * M1;  // vF fragment-ordered V (written by V-GEMM)
  u16* qln = xb;
  u16* at  = qpre;

  k_classify<<<1, 64, 0, stream>>>(
      (const u16*)d_in[0], (const u16*)d_in[1], (const u16*)d_in[2], (const u16*)d_in[3],
      (const u16*)d_in[4], (const u16*)d_in[5], (const u16*)d_in[6], (const u16*)d_in[7],
      (const u16*)d_in[8], (const u16*)d_in[9], (const u16*)d_in[10], flags);

  k_convert_x<<<2048, 256, 0, stream>>>(d_in[0], xb, flags);
  k_transpose_w<<<dim3(16, 16, 4), 256, 0, stream>>>(d_in[1], d_in[3], d_in[5], d_in[7], wt, flags);
  k_gemm_qkv<<<dim3(8, 32, 3), 256, 0, stream>>>(xb, wt, d_in[2], d_in[4], d_in[6], flags,
                                                 qpre, kb, vtb);
  k_layernorm<<<4096, 256, 0, stream>>>(qpre, d_in[9], d_in[10], flags, qln);
  k_attention<<<256, 256, 0, stream>>>(qln, kb, vtb, at);
  k_gemm_out<<<dim3(8, 64), 256, 0, stream>>>(at, wt + 3 * M1, d_in[8], flags, d_out);
}